// Round 3
// baseline (1119.596 us; speedup 1.0000x reference)
//
#include <hip/hip_runtime.h>
#include <hip/hip_bf16.h>
#include <stdint.h>

#define T_TOK 8192
#define H_DIM 1024
#define F_DIM 4096
#define NEXP  8
#define CAP        18432   // 16384 + 8*256 worst-case 256-aligned padding
#define CTILES     72      // CAP/256

typedef __attribute__((ext_vector_type(8))) short bf16x8;
typedef __attribute__((ext_vector_type(4))) float f32x4;

#define AS1 __attribute__((address_space(1)))
#define AS3 __attribute__((address_space(3)))

__device__ __forceinline__ void gload_lds16(const void* g, void* l) {
  __builtin_amdgcn_global_load_lds((const AS1 void*)g, (AS3 void*)l, 16, 0, 0);
}

struct TK { int i0, i1; float w0, w1; };

// ---------------- router: fp32 logits, softmax, top-2, renorm ----------------
__global__ __launch_bounds__(256) void router_kernel(
    const float* __restrict__ x, const float* __restrict__ gw,
    float* __restrict__ logits, int* __restrict__ counts, TK* __restrict__ tk)
{
  const int lane = threadIdx.x & 63;
  const int t = blockIdx.x * 4 + (threadIdx.x >> 6);
  const float* xp = x + (size_t)t * H_DIM;
  float xr[16];
#pragma unroll
  for (int i = 0; i < 16; ++i) xr[i] = xp[lane + i * 64];
  float lg[NEXP];
#pragma unroll
  for (int e = 0; e < NEXP; ++e) {
    const float* gp = gw + e * H_DIM;
    float acc = 0.f;
#pragma unroll
    for (int i = 0; i < 16; ++i) acc += xr[i] * gp[lane + i * 64];
#pragma unroll
    for (int s = 32; s > 0; s >>= 1) acc += __shfl_xor(acc, s, 64);
    lg[e] = acc;
  }
  if (lane < NEXP) logits[(size_t)t * NEXP + lane] = lg[lane];
  if (lane == 0) {
    int i0 = 0; float m0 = lg[0];
#pragma unroll
    for (int e = 1; e < NEXP; ++e) if (lg[e] > m0) { m0 = lg[e]; i0 = e; }
    int i1 = -1; float m1 = -1e30f;
#pragma unroll
    for (int e = 0; e < NEXP; ++e) if (e != i0 && lg[e] > m1) { m1 = lg[e]; i1 = e; }
    float r = expf(m1 - m0);            // top-2 renormalized softmax
    float w0 = 1.f / (1.f + r);
    float w1 = r / (1.f + r);
    TK v; v.i0 = i0; v.i1 = i1; v.w0 = w0; v.w1 = w1;
    tk[t] = v;
    atomicAdd(&counts[i0], 1);
    atomicAdd(&counts[i1], 1);
  }
}

// ---------------- scan: 256-aligned segment offsets + tile->expert map ------
__global__ __launch_bounds__(256) void scan_kernel(
    const int* __restrict__ counts, int* __restrict__ offs,
    int* __restrict__ cursor, int* __restrict__ tile_expert)
{
  __shared__ int so[NEXP + 1];
  const int tid = threadIdx.x;
  if (tid == 0) {
    int o = 0;
    for (int e = 0; e < NEXP; ++e) {
      so[e] = o; offs[e] = o; cursor[e] = o;
      o += (counts[e] + 255) & ~255;
    }
    so[NEXP] = o; offs[NEXP] = o;
  }
  __syncthreads();
  for (int ti = tid; ti < CTILES; ti += 256) {
    int row = ti * 256;
    int e = NEXP - 1;
#pragma unroll
    for (int k = 0; k < NEXP; ++k)
      if (row >= so[k] && row < so[k + 1]) { e = k; break; }
    tile_expert[ti] = e;   // tail tiles keep e=7; their weights are 0
  }
}

// ---------------- scatter: token -> slot in expert-sorted list --------------
__global__ __launch_bounds__(256) void scatter_kernel(
    const TK* __restrict__ tk, int* __restrict__ cursor,
    int* __restrict__ pair_tok, float* __restrict__ pair_w,
    int2* __restrict__ inv)
{
  int t = blockIdx.x * 256 + threadIdx.x;
  if (t >= T_TOK) return;
  TK v = tk[t];
  int p0 = atomicAdd(&cursor[v.i0], 1);
  pair_tok[p0] = t; pair_w[p0] = v.w0;
  int p1 = atomicAdd(&cursor[v.i1], 1);
  pair_tok[p1] = t; pair_w[p1] = v.w1;
  inv[t] = make_int2(p0, p1);
}

// ---------------- gather: x fp32 rows -> bf16 xg (expert-sorted) ------------
union Pack8 { __hip_bfloat16 o[8]; uint4 u; };

__global__ __launch_bounds__(256) void gather_kernel(
    const float* __restrict__ x, const int* __restrict__ pair_tok,
    __hip_bfloat16* __restrict__ xg)
{
  int idx = blockIdx.x * 256 + threadIdx.x;   // CAP*128 threads
  int row = idx >> 7;
  int c8  = (idx & 127) << 3;
  int tok = pair_tok[row];                    // pad rows: tok=0, harmless
  const float4* src = reinterpret_cast<const float4*>(x + (size_t)tok * H_DIM + c8);
  float4 a = src[0], b = src[1];
  Pack8 pk;
  pk.o[0] = __float2bfloat16(a.x); pk.o[1] = __float2bfloat16(a.y);
  pk.o[2] = __float2bfloat16(a.z); pk.o[3] = __float2bfloat16(a.w);
  pk.o[4] = __float2bfloat16(b.x); pk.o[5] = __float2bfloat16(b.y);
  pk.o[6] = __float2bfloat16(b.z); pk.o[7] = __float2bfloat16(b.w);
  *reinterpret_cast<uint4*>(xg + (size_t)row * H_DIM + c8) = pk.u;
}

// ---------------- weight convert fp32 -> bf16 -------------------------------
__global__ __launch_bounds__(256) void convert_kernel(
    const float* __restrict__ src, __hip_bfloat16* __restrict__ dst, long long n)
{
  long long i = ((long long)blockIdx.x * 256 + threadIdx.x) * 8;
  if (i >= n) return;
  float4 a = *reinterpret_cast<const float4*>(src + i);
  float4 b = *reinterpret_cast<const float4*>(src + i + 4);
  Pack8 pk;
  pk.o[0] = __float2bfloat16(a.x); pk.o[1] = __float2bfloat16(a.y);
  pk.o[2] = __float2bfloat16(a.z); pk.o[3] = __float2bfloat16(a.w);
  pk.o[4] = __float2bfloat16(b.x); pk.o[5] = __float2bfloat16(b.y);
  pk.o[6] = __float2bfloat16(b.z); pk.o[7] = __float2bfloat16(b.w);
  *reinterpret_cast<uint4*>(dst + i) = pk.u;
}

// ===== LDS tile layout: rows of 64 bf16 (128B, 8 x 16B slots).
// T2 XOR swizzle: phys slot p at row r holds logical slot p ^ (r&7).
// Write side: linear global_load_lds dest + pre-swizzled GLOBAL source slot
// (lslot = (tid&7) ^ (rs&7), rs = row-within-64-row-chunk; chunk*64 ≡ 0 mod 8
// so row&7 == rs&7).  Read side: pslot = (ks*4+lk) ^ (l16&7).
// 16 lanes of an MFMA frag read hit all 8 slots twice = 2 lanes/bank = free.

// ---------------- GEMM1: h = silu(Xg @ w1[e]^T) * (Xg @ w3[e]^T) ------------
// BM=256, BF=128, BK=64. 512 thr = 8 waves (4M x 2N). Per wave: 64x64 output,
// DUAL accumulators (c1,c3) so silu-combine is in-thread. Double-buffered LDS
// (128 KB), one barrier per K-step, stage issued before compute (overlap).
__global__ __launch_bounds__(512, 2) void gemm1_kernel(
    const __hip_bfloat16* __restrict__ xg,
    const __hip_bfloat16* __restrict__ w1b,
    const __hip_bfloat16* __restrict__ w3b,
    const int* __restrict__ tile_expert,
    __hip_bfloat16* __restrict__ h)
{
  __shared__ __hip_bfloat16 sA[2][256 * 64];   // 64 KB
  __shared__ __hip_bfloat16 sB1[2][128 * 64];  // 32 KB
  __shared__ __hip_bfloat16 sB3[2][128 * 64];  // 32 KB

  const int n_ = blockIdx.x;                    // 0..2303
  const int swz = (n_ & 7) * 288 + (n_ >> 3);   // bijective XCD swizzle (T1)
  const int tm = swz >> 5;                      // 0..71 (A panel; slow per XCD)
  const int tf = swz & 31;                      // 0..31 (f tile; fast)
  const int e  = tile_expert[tm];
  const int tid = threadIdx.x;

  const __hip_bfloat16* A  = xg  + (size_t)tm * 256 * H_DIM;
  const __hip_bfloat16* B1 = w1b + (size_t)e * F_DIM * H_DIM + (size_t)tf * 128 * H_DIM;
  const __hip_bfloat16* B3 = w3b + (size_t)e * F_DIM * H_DIM + (size_t)tf * 128 * H_DIM;

  // staging map: 8 chunks of 8KB; chunk = 64 rows x 128B; thread -> 16B
  const int rs    = tid >> 3;                   // row within chunk 0..63
  const int lslot = (tid & 7) ^ (rs & 7);       // pre-swizzled global slot
  const int ldst  = tid * 8;                    // elems within chunk (linear)
  const __hip_bfloat16* As  = A  + (size_t)rs * H_DIM + lslot * 8;
  const __hip_bfloat16* B1s = B1 + (size_t)rs * H_DIM + lslot * 8;
  const __hip_bfloat16* B3s = B3 + (size_t)rs * H_DIM + lslot * 8;

  // frag read precompute
  const int wv = tid >> 6, lane = tid & 63;
  const int wr = wv >> 1, wc = wv & 1;          // 4M x 2N
  const int l16 = lane & 15, lk = lane >> 4;
  int rowA[4], rowB[4];
#pragma unroll
  for (int m = 0; m < 4; ++m) rowA[m] = (wr * 64 + m * 16 + l16) * 64;
#pragma unroll
  for (int n = 0; n < 4; ++n) rowB[n] = (wc * 64 + n * 16 + l16) * 64;
  const int ps[2] = { ((0 + lk) ^ (l16 & 7)) * 8, ((4 + lk) ^ (l16 & 7)) * 8 };

  f32x4 acc1[4][4] = {};
  f32x4 acc3[4][4] = {};

  // prologue: stage kt=0 into buf 0
#pragma unroll
  for (int c = 0; c < 4; ++c)
    gload_lds16(As + (size_t)c * 64 * H_DIM, &sA[0][c * 4096 + ldst]);
#pragma unroll
  for (int c = 0; c < 2; ++c) {
    gload_lds16(B1s + (size_t)c * 64 * H_DIM, &sB1[0][c * 4096 + ldst]);
    gload_lds16(B3s + (size_t)c * 64 * H_DIM, &sB3[0][c * 4096 + ldst]);
  }
  __syncthreads();

  int cur = 0;
  for (int kt = 0; kt < H_DIM / 64; ++kt) {
    const int nxt = cur ^ 1;
    if (kt + 1 < H_DIM / 64) {
      const int gk = (kt + 1) * 64;
#pragma unroll
      for (int c = 0; c < 4; ++c)
        gload_lds16(As + (size_t)c * 64 * H_DIM + gk, &sA[nxt][c * 4096 + ldst]);
#pragma unroll
      for (int c = 0; c < 2; ++c) {
        gload_lds16(B1s + (size_t)c * 64 * H_DIM + gk, &sB1[nxt][c * 4096 + ldst]);
        gload_lds16(B3s + (size_t)c * 64 * H_DIM + gk, &sB3[nxt][c * 4096 + ldst]);
      }
    }
    const __hip_bfloat16* sAc  = sA[cur];
    const __hip_bfloat16* sB1c = sB1[cur];
    const __hip_bfloat16* sB3c = sB3[cur];
#pragma unroll
    for (int ks = 0; ks < 2; ++ks) {
      bf16x8 af[4], b1f[4], b3f[4];
#pragma unroll
      for (int m = 0; m < 4; ++m)
        af[m] = *reinterpret_cast<const bf16x8*>(&sAc[rowA[m] + ps[ks]]);
#pragma unroll
      for (int n = 0; n < 4; ++n) {
        b1f[n] = *reinterpret_cast<const bf16x8*>(&sB1c[rowB[n] + ps[ks]]);
        b3f[n] = *reinterpret_cast<const bf16x8*>(&sB3c[rowB[n] + ps[ks]]);
      }
      __builtin_amdgcn_s_setprio(1);
#pragma unroll
      for (int m = 0; m < 4; ++m)
#pragma unroll
        for (int n = 0; n < 4; ++n) {
          acc1[m][n] = __builtin_amdgcn_mfma_f32_16x16x32_bf16(af[m], b1f[n], acc1[m][n], 0, 0, 0);
          acc3[m][n] = __builtin_amdgcn_mfma_f32_16x16x32_bf16(af[m], b3f[n], acc3[m][n], 0, 0, 0);
        }
      __builtin_amdgcn_s_setprio(0);
    }
    __syncthreads();   // drains vmcnt (next buf staged) + orders buf reuse
    cur = nxt;
  }

  __hip_bfloat16* hp = h + (size_t)tm * 256 * F_DIM + (size_t)tf * 128;
#pragma unroll
  for (int m = 0; m < 4; ++m)
#pragma unroll
    for (int n = 0; n < 4; ++n)
#pragma unroll
      for (int j = 0; j < 4; ++j) {
        int row = wr * 64 + m * 16 + lk * 4 + j;   // C/D: col=lane&15, row=(lane>>4)*4+j
        int col = wc * 64 + n * 16 + l16;
        float c1 = acc1[m][n][j];
        float c3 = acc3[m][n][j];
        float s  = c1 / (1.f + expf(-c1));
        hp[(size_t)row * F_DIM + col] = __float2bfloat16(s * c3);
      }
}

// ---------------- GEMM2: y[slot] = w[slot] * (h @ w2[e]^T)  (no atomics) ----
// Same skeleton: BM=256, BN=128, BK=64, dbuf, 1 barrier/K-step.
__global__ __launch_bounds__(512, 2) void gemm2_kernel(
    const __hip_bfloat16* __restrict__ h,
    const __hip_bfloat16* __restrict__ w2b,
    const int* __restrict__ tile_expert,
    const float* __restrict__ pair_w,
    float* __restrict__ y)
{
  __shared__ __hip_bfloat16 sA[2][256 * 64];   // 64 KB
  __shared__ __hip_bfloat16 sB[2][128 * 64];   // 32 KB

  const int n_ = blockIdx.x;                    // 0..575
  const int swz = (n_ & 7) * 72 + (n_ >> 3);
  const int tm = swz >> 3;                      // 0..71
  const int tn = swz & 7;                       // 0..7
  const int e  = tile_expert[tm];
  const int tid = threadIdx.x;

  const __hip_bfloat16* A = h   + (size_t)tm * 256 * F_DIM;
  const __hip_bfloat16* B = w2b + (size_t)e * H_DIM * F_DIM + (size_t)tn * 128 * F_DIM;

  const int rs    = tid >> 3;
  const int lslot = (tid & 7) ^ (rs & 7);
  const int ldst  = tid * 8;
  const __hip_bfloat16* As = A + (size_t)rs * F_DIM + lslot * 8;
  const __hip_bfloat16* Bs = B + (size_t)rs * F_DIM + lslot * 8;

  const int wv = tid >> 6, lane = tid & 63;
  const int wr = wv >> 1, wc = wv & 1;
  const int l16 = lane & 15, lk = lane >> 4;
  int rowA[4], rowB[4];
#pragma unroll
  for (int m = 0; m < 4; ++m) rowA[m] = (wr * 64 + m * 16 + l16) * 64;
#pragma unroll
  for (int n = 0; n < 4; ++n) rowB[n] = (wc * 64 + n * 16 + l16) * 64;
  const int ps[2] = { ((0 + lk) ^ (l16 & 7)) * 8, ((4 + lk) ^ (l16 & 7)) * 8 };

  f32x4 acc[4][4] = {};

#pragma unroll
  for (int c = 0; c < 4; ++c)
    gload_lds16(As + (size_t)c * 64 * F_DIM, &sA[0][c * 4096 + ldst]);
#pragma unroll
  for (int c = 0; c < 2; ++c)
    gload_lds16(Bs + (size_t)c * 64 * F_DIM, &sB[0][c * 4096 + ldst]);
  __syncthreads();

  int cur = 0;
  for (int kt = 0; kt < F_DIM / 64; ++kt) {
    const int nxt = cur ^ 1;
    if (kt + 1 < F_DIM / 64) {
      const int gk = (kt + 1) * 64;
#pragma unroll
      for (int c = 0; c < 4; ++c)
        gload_lds16(As + (size_t)c * 64 * F_DIM + gk, &sA[nxt][c * 4096 + ldst]);
#pragma unroll
      for (int c = 0; c < 2; ++c)
        gload_lds16(Bs + (size_t)c * 64 * F_DIM + gk, &sB[nxt][c * 4096 + ldst]);
    }
    const __hip_bfloat16* sAc = sA[cur];
    const __hip_bfloat16* sBc = sB[cur];
#pragma unroll
    for (int ks = 0; ks < 2; ++ks) {
      bf16x8 af[4], bf[4];
#pragma unroll
      for (int m = 0; m < 4; ++m)
        af[m] = *reinterpret_cast<const bf16x8*>(&sAc[rowA[m] + ps[ks]]);
#pragma unroll
      for (int n = 0; n < 4; ++n)
        bf[n] = *reinterpret_cast<const bf16x8*>(&sBc[rowB[n] + ps[ks]]);
      __builtin_amdgcn_s_setprio(1);
#pragma unroll
      for (int m = 0; m < 4; ++m)
#pragma unroll
        for (int n = 0; n < 4; ++n)
          acc[m][n] = __builtin_amdgcn_mfma_f32_16x16x32_bf16(af[m], bf[n], acc[m][n], 0, 0, 0);
      __builtin_amdgcn_s_setprio(0);
    }
    __syncthreads();
    cur = nxt;
  }

#pragma unroll
  for (int m = 0; m < 4; ++m)
#pragma unroll
    for (int j = 0; j < 4; ++j) {
      int rowg = tm * 256 + wr * 64 + m * 16 + lk * 4 + j;   // slot index
      float w = pair_w[rowg];                                // 0 for pad rows
      float* op = y + (size_t)rowg * H_DIM + tn * 128 + wc * 64;
#pragma unroll
      for (int n = 0; n < 4; ++n)
        op[n * 16 + l16] = w * acc[m][n][j];
    }
}

// ---------------- combine: out[t] = y[p0] + y[p1] ---------------------------
__global__ __launch_bounds__(256) void combine_kernel(
    const float* __restrict__ y, const int2* __restrict__ inv,
    float* __restrict__ out)
{
  int idx = blockIdx.x * 256 + threadIdx.x;
  int t  = idx >> 8;
  int c  = (idx & 255) << 2;
  int2 p = inv[t];
  float4 a = *reinterpret_cast<const float4*>(y + (size_t)p.x * H_DIM + c);
  float4 b = *reinterpret_cast<const float4*>(y + (size_t)p.y * H_DIM + c);
  float4 o; o.x = a.x + b.x; o.y = a.y + b.y; o.z = a.z + b.z; o.w = a.w + b.w;
  *reinterpret_cast<float4*>(out + (size_t)t * H_DIM + c) = o;
}

// ---------------- workspace layout ------------------------------------------
#define WS_COUNTS   0
#define WS_CURSOR   32
#define WS_OFFS     64
#define WS_TILEEXP  128       // 72*4 = 288 B
#define WS_TK       1024      // 8192*16 = 131072
#define WS_PAIRTOK  132096    // 18432*4 = 73728
#define WS_PAIRW    205824    // 73728
#define WS_ZERO_BYTES 279552  // counts..pair_w zeroed per call
#define WS_INV      279552    // int2[8192] = 65536 (fully written)
#define WS_XG       345088ll
#define WS_W1       (WS_XG + 37748736ll)    //  38093824
#define WS_W3       (WS_W1 + 67108864ll)    // 105202688
#define WS_W2       (WS_W3 + 67108864ll)    // 172311552
#define WS_H        (WS_W2 + 67108864ll)    // 239420416, h = 151 MB
// y (CAP*1024 fp32 = 75.5 MB) aliases xg+w1b (both dead after gemm1, both
// rewritten every call before gemm1 runs).
#define WS_Y        WS_XG

extern "C" void kernel_launch(void* const* d_in, const int* in_sizes, int n_in,
                              void* d_out, int out_size, void* d_ws, size_t ws_size,
                              hipStream_t stream) {
  const float* x  = (const float*)d_in[0];
  const float* gw = (const float*)d_in[1];
  const float* w1 = (const float*)d_in[2];
  const float* w3 = (const float*)d_in[3];
  const float* w2 = (const float*)d_in[4];
  float* out    = (float*)d_out;
  float* logits = out + (size_t)T_TOK * H_DIM;

  char* ws = (char*)d_ws;
  int*   counts   = (int*)(ws + WS_COUNTS);
  int*   cursor   = (int*)(ws + WS_CURSOR);
  int*   offs     = (int*)(ws + WS_OFFS);
  int*   tile_exp = (int*)(ws + WS_TILEEXP);
  TK*    tk       = (TK*)(ws + WS_TK);
  int*   pair_tok = (int*)(ws + WS_PAIRTOK);
  float* pair_w   = (float*)(ws + WS_PAIRW);
  int2*  inv      = (int2*)(ws + WS_INV);
  __hip_bfloat16* xg  = (__hip_bfloat16*)(ws + WS_XG);
  __hip_bfloat16* w1b = (__hip_bfloat16*)(ws + WS_W1);
  __hip_bfloat16* w3b = (__hip_bfloat16*)(ws + WS_W3);
  __hip_bfloat16* w2b = (__hip_bfloat16*)(ws + WS_W2);
  __hip_bfloat16* hbuf = (__hip_bfloat16*)(ws + WS_H);
  float* ybuf = (float*)(ws + WS_Y);

  hipMemsetAsync(d_ws, 0, WS_ZERO_BYTES, stream);

  const long long nW = (long long)NEXP * F_DIM * H_DIM;   // 33,554,432
  convert_kernel<<<16384, 256, 0, stream>>>(w1, w1b, nW);
  convert_kernel<<<16384, 256, 0, stream>>>(w3, w3b, nW);
  convert_kernel<<<16384, 256, 0, stream>>>(w2, w2b, nW);

  router_kernel<<<T_TOK / 4, 256, 0, stream>>>(x, gw, logits, counts, tk);
  scan_kernel<<<1, 256, 0, stream>>>(counts, offs, cursor, tile_exp);
  scatter_kernel<<<T_TOK / 256, 256, 0, stream>>>(tk, cursor, pair_tok, pair_w, inv);
  gather_kernel<<<(CAP * 128) / 256, 256, 0, stream>>>(x, pair_tok, xg);

  gemm1_kernel<<<CTILES * (F_DIM / 128), 512, 0, stream>>>(
      xg, w1b, w3b, tile_exp, hbuf);
  gemm2_kernel<<<CTILES * (H_DIM / 128), 512, 0, stream>>>(
      hbuf, w2b, tile_exp, pair_w, ybuf);
  combine_kernel<<<(T_TOK * H_DIM / 4) / 256, 256, 0, stream>>>(ybuf, inv, out);
}